// Round 4
// baseline (314.112 us; speedup 1.0000x reference)
//
#include <hip/hip_runtime.h>
#include <stdint.h>

typedef int v4i __attribute__((ext_vector_type(4)));

#define M_DIM 8192   // B*S = 2*4096
#define N_DIM 8192   // OUT
#define K_DIM 2048   // IN
#define RISKY_TAU 1e-4f
#define BUCKET_CAP 1024

// async global->LDS, 16B per lane (dest = wave-uniform base + lane*16)
#define ASYNC16(g, l) __builtin_amdgcn_global_load_lds(                        \
    (const __attribute__((address_space(1))) void*)(uintptr_t)(g),             \
    (__attribute__((address_space(3))) void*)(uint32_t)(uintptr_t)(l), 16, 0, 0)

// ---------------- 1) numpy-pairwise f32 sum of |w| ----------------
__global__ __launch_bounds__(256) void abssum_stage1(const float* __restrict__ w,
                                                     float* __restrict__ s1) {
  int b = blockIdx.x * 256 + threadIdx.x;  // 131072 leaf blocks of 128
  const float* p = w + (size_t)b * 128;
  float r[8];
#pragma unroll
  for (int j = 0; j < 8; j++) r[j] = fabsf(p[j]);
  for (int i = 8; i < 128; i += 8) {
#pragma unroll
    for (int j = 0; j < 8; j++) r[j] += fabsf(p[i + j]);
  }
  s1[b] = ((r[0] + r[1]) + (r[2] + r[3])) + ((r[4] + r[5]) + (r[6] + r[7]));
}

__global__ __launch_bounds__(256) void abssum_stage2(const float* __restrict__ s1,
                                                     float* __restrict__ s2) {
  int t = blockIdx.x * 256 + threadIdx.x;  // 4096 threads
  float v[32];
#pragma unroll
  for (int i = 0; i < 32; i++) v[i] = s1[t * 32 + i];
#pragma unroll
  for (int s = 1; s < 32; s *= 2) {
#pragma unroll
    for (int i = 0; i < 32; i += 2 * s) v[i] += v[i + s];
  }
  s2[t] = v[0];
}

__global__ __launch_bounds__(256) void gamma_stage3(const float* __restrict__ s2,
                                                    float* __restrict__ gp) {
  int t = threadIdx.x;  // 256 threads, one block
  float v[16];
#pragma unroll
  for (int i = 0; i < 16; i++) v[i] = s2[t * 16 + i];
#pragma unroll
  for (int s = 1; s < 16; s *= 2) {
#pragma unroll
    for (int i = 0; i < 16; i += 2 * s) v[i] += v[i + s];
  }
  __shared__ float sm[256];
  sm[t] = v[0];
  for (int s = 1; s < 256; s *= 2) {
    __syncthreads();
    if ((t & (2 * s - 1)) == 0) sm[t] += sm[t + s];
  }
  __syncthreads();
  if (t == 0) {
    float g = sm[0] * 0x1p-24f;  // /(8192*2048), exact pow2 scale
    gp[0] = fmaxf(g, 1e-5f);
  }
}

__global__ void zero_counts(int* __restrict__ counts) {
  counts[threadIdx.x] = 0;
}

// ---------------- 2) ternary weight quant + risky-midpoint detection ----------------
// risky: |(|w|/gamma) - 0.5| < TAU  ->  effective weight = sign(w)*0.5 (int-exact via
// doubled accumulator in the GEMM). Entry packed: k | n<<11 | sbit<<24.
__global__ __launch_bounds__(256) void wq_kernel(const float4* __restrict__ w4,
                                                 const float* __restrict__ gp,
                                                 int* __restrict__ wq,
                                                 int* __restrict__ counts,
                                                 int* __restrict__ buckets) {
  int i = blockIdx.x * 256 + threadIdx.x;
  float g = gp[0];
  float4 v = w4[i];
  float e[4] = {v.x, v.y, v.z, v.w};
  int q[4];
#pragma unroll
  for (int c = 0; c < 4; c++) {
    q[c] = (int)rintf(fminf(fmaxf(e[c] / g, -1.0f), 1.0f));
    float t = fabsf(e[c]) / g;
    if (fabsf(t - 0.5f) < RISKY_TAU) {
      int flat = i * 4 + c;
      int n = flat >> 11;          // weight row (output col)
      int k = flat & 2047;
      // s2 = (q==0) ? sign(w) : -sign(w); sbit = (s2 < 0)
      int sgn_neg = (e[c] < 0.0f) ? 1 : 0;
      int sbit = (q[c] == 0) ? sgn_neg : (1 - sgn_neg);
      int b = n >> 7;
      int idx = atomicAdd(&counts[b], 1);
      if (idx < BUCKET_CAP)
        buckets[b * BUCKET_CAP + idx] = k | (n << 11) | (sbit << 24);
    }
  }
  wq[i] = (q[0] & 0xFF) | ((q[1] & 0xFF) << 8) | ((q[2] & 0xFF) << 16) | ((q[3] & 0xFF) << 24);
}

// ---------------- 3) fused LayerNorm + absmax int8 quant (one block per row) ----------------
__global__ __launch_bounds__(256) void lnq_kernel(const float* __restrict__ x,
                                                  const float* __restrict__ gp,
                                                  int8_t* __restrict__ xq,
                                                  float* __restrict__ scales) {
  const int row = blockIdx.x;
  const int t = threadIdx.x;
  const float4* xr = (const float4*)(x + (size_t)row * K_DIM);
  float4 a = xr[t];
  float4 b = xr[t + 256];
  double v[8] = {a.x, a.y, a.z, a.w, b.x, b.y, b.z, b.w};
  double s = 0.0, ss = 0.0;
#pragma unroll
  for (int i = 0; i < 8; i++) { s += v[i]; ss += v[i] * v[i]; }
  __shared__ double sm1[256], sm2[256];
  sm1[t] = s; sm2[t] = ss;
  __syncthreads();
  for (int off = 128; off > 0; off >>= 1) {
    if (t < off) { sm1[t] += sm1[t + off]; sm2[t] += sm2[t + off]; }
    __syncthreads();
  }
  double mu = sm1[0] * (1.0 / 2048.0);
  double var = sm2[0] * (1.0 / 2048.0) - mu * mu;  // biased variance
  double inv = 1.0 / sqrt(var + 1e-5);
  __syncthreads();
  double mx = 0.0;
#pragma unroll
  for (int i = 0; i < 8; i++) {
    v[i] = (v[i] - mu) * inv;
    double av = fabs(v[i]);
    if (av > mx) mx = av;
  }
  sm1[t] = mx;
  __syncthreads();
  for (int off = 128; off > 0; off >>= 1) {
    if (t < off) sm1[t] = fmax(sm1[t], sm1[t + off]);
    __syncthreads();
  }
  double eta = fmax(sm1[0], 1e-5);
  double r = 127.0 / eta;
  int q[8];
#pragma unroll
  for (int i = 0; i < 8; i++) {
    double qq = rint(v[i] * r);  // round-half-even, then clip
    qq = fmin(fmax(qq, -128.0), 127.0);
    q[i] = (int)qq;
  }
  int p0 = (q[0] & 0xFF) | ((q[1] & 0xFF) << 8) | ((q[2] & 0xFF) << 16) | ((q[3] & 0xFF) << 24);
  int p1 = (q[4] & 0xFF) | ((q[5] & 0xFF) << 8) | ((q[6] & 0xFF) << 16) | ((q[7] & 0xFF) << 24);
  int* orow = (int*)(xq + (size_t)row * K_DIM);
  orow[t] = p0;
  orow[t + 256] = p1;
  if (t == 0) scales[row] = (float)((double)gp[0] * eta * (1.0 / 127.0));
}

// ---------------- 4) int8 MFMA GEMM with doubled-acc midpoint correction ----------------
__global__ __launch_bounds__(256) void gemm_i8_kernel(const int8_t* __restrict__ A,
                                                      const int8_t* __restrict__ B,
                                                      const float* __restrict__ scales,
                                                      const float* __restrict__ bias,
                                                      const int* __restrict__ counts,
                                                      const int* __restrict__ buckets,
                                                      float* __restrict__ C) {
  __shared__ alignas(16) int8_t lds[2 * 128 * 64];  // A at 0, B at 8192
  const int tid = threadIdx.x;
  const int wave = tid >> 6;
  const int lane = tid & 63;
  const int brow = blockIdx.y * 128;
  const int bcol = blockIdx.x * 128;

  const int rA0 = (wave * 2 + 0) * 16 + (lane >> 2);
  const int rA1 = (wave * 2 + 1) * 16 + (lane >> 2);
  const int c16 = lane & 3;
  const int cA0 = ((c16 ^ ((rA0 >> 1) & 3)) << 4);
  const int cA1 = ((c16 ^ ((rA1 >> 1) & 3)) << 4);
  const int8_t* gA0 = A + (size_t)(brow + rA0) * K_DIM + cA0;
  const int8_t* gA1 = A + (size_t)(brow + rA1) * K_DIM + cA1;
  const int8_t* gB0 = B + (size_t)(bcol + rA0) * K_DIM + cA0;
  const int8_t* gB1 = B + (size_t)(bcol + rA1) * K_DIM + cA1;
  int8_t* lA0 = lds + (wave * 2 + 0) * 1024;
  int8_t* lA1 = lds + (wave * 2 + 1) * 1024;
  int8_t* lB0 = lds + 8192 + (wave * 2 + 0) * 1024;
  int8_t* lB1 = lds + 8192 + (wave * 2 + 1) * 1024;

  const int wr = wave >> 1, wc = wave & 1;
  int aoff[4], boff[4];
#pragma unroll
  for (int i = 0; i < 4; i++) {
    int lr = wr * 64 + i * 16 + (lane & 15);
    aoff[i] = lr * 64 + ((((lane >> 4) ^ ((lr >> 1) & 3))) << 4);
    int lc = wc * 64 + i * 16 + (lane & 15);
    boff[i] = 8192 + lc * 64 + ((((lane >> 4) ^ ((lc >> 1) & 3))) << 4);
  }

  v4i acc[4][4];
  const v4i vzero = {0, 0, 0, 0};
#pragma unroll
  for (int i = 0; i < 4; i++)
#pragma unroll
    for (int j = 0; j < 4; j++) acc[i][j] = vzero;

  for (int kt = 0; kt < K_DIM; kt += 64) {
    ASYNC16(gA0 + kt, lA0);
    ASYNC16(gA1 + kt, lA1);
    ASYNC16(gB0 + kt, lB0);
    ASYNC16(gB1 + kt, lB1);
    __syncthreads();
    v4i af[4], bf[4];
#pragma unroll
    for (int i = 0; i < 4; i++) af[i] = *(const v4i*)(lds + aoff[i]);
#pragma unroll
    for (int j = 0; j < 4; j++) bf[j] = *(const v4i*)(lds + boff[j]);
#pragma unroll
    for (int i = 0; i < 4; i++)
#pragma unroll
      for (int j = 0; j < 4; j++)
        acc[i][j] = __builtin_amdgcn_mfma_i32_16x16x64_i8(af[i], bf[j], acc[i][j], 0, 0, 0);
    __syncthreads();
  }

  // double accumulators (so midpoint = odd integer), then apply risky corrections
#pragma unroll
  for (int i = 0; i < 4; i++)
#pragma unroll
    for (int j = 0; j < 4; j++) acc[i][j] = acc[i][j] + acc[i][j];

  const int crow0 = brow + wr * 64;
  const int ccol0 = bcol + wc * 64;

#define CORR(J)                                                                \
  {                                                                            \
    _Pragma("unroll") for (int i = 0; i < 4; i++) {                            \
      _Pragma("unroll") for (int r = 0; r < 4; r++) {                          \
        int grow = crow0 + i * 16 + ((lane >> 4) << 2) + r;                    \
        int xv = (int)A[(size_t)grow * K_DIM + k];                             \
        acc[i][J][r] += sv * xv;                                               \
      }                                                                        \
    }                                                                          \
  }

  {
    int bkt = bcol >> 7;
    int cnt = counts[bkt];
    if (cnt > BUCKET_CAP) cnt = BUCKET_CAP;
    const int* bk = buckets + bkt * BUCKET_CAP;
    for (int e = 0; e < cnt; ++e) {
      int word = bk[e];
      int k = word & 2047;
      int n = (word >> 11) & 8191;
      int sv = ((word >> 24) & 1) ? -1 : 1;
      int lc = n - bcol;  // in [0,128)
      if (((lc >> 6) & 1) == wc && (lc & 15) == (lane & 15)) {
        int j = (lc >> 4) & 3;
        switch (j) {
          case 0: CORR(0); break;
          case 1: CORR(1); break;
          case 2: CORR(2); break;
          case 3: CORR(3); break;
        }
      }
    }
  }
#undef CORR

  // epilogue: C[m][n] = (2*acc_corrected) * (scale_m/2) + bias[n]
#pragma unroll
  for (int i = 0; i < 4; i++) {
#pragma unroll
    for (int r = 0; r < 4; r++) {
      int grow = crow0 + i * 16 + ((lane >> 4) << 2) + r;
      float sc = scales[grow] * 0.5f;
      float* crow = C + (size_t)grow * N_DIM;
#pragma unroll
      for (int j = 0; j < 4; j++) {
        int gcol = ccol0 + j * 16 + (lane & 15);
        crow[gcol] = (float)acc[i][j][r] * sc + bias[gcol];
      }
    }
  }
}

extern "C" void kernel_launch(void* const* d_in, const int* in_sizes, int n_in,
                              void* d_out, int out_size, void* d_ws, size_t ws_size,
                              hipStream_t stream) {
  const float* x = (const float*)d_in[0];
  const float* w = (const float*)d_in[1];
  const float* bias = (const float*)d_in[2];
  float* out = (float*)d_out;

  char* ws = (char*)d_ws;
  float* s1 = (float*)(ws);                          // 512 KiB
  float* s2 = (float*)(ws + 0x100000);               // 16 KiB
  float* gamma_f = (float*)(ws + 0x110000);          // 4 B
  float* scales = (float*)(ws + 0x120000);           // 32 KiB
  int* counts = (int*)(ws + 0x130000);               // 64 * 4 B
  int* buckets = (int*)(ws + 0x131000);              // 64 * 1024 * 4 B = 256 KiB
  int8_t* Aq = (int8_t*)(ws + 0x200000);                             // 16 MiB
  int8_t* Wq = (int8_t*)(ws + 0x200000 + (size_t)M_DIM * K_DIM);     // 16 MiB

  abssum_stage1<<<512, 256, 0, stream>>>(w, s1);
  abssum_stage2<<<16, 256, 0, stream>>>(s1, s2);
  gamma_stage3<<<1, 256, 0, stream>>>(s2, gamma_f);
  zero_counts<<<1, 64, 0, stream>>>(counts);
  wq_kernel<<<(N_DIM * K_DIM / 4 + 255) / 256, 256, 0, stream>>>(
      (const float4*)w, gamma_f, (int*)Wq, counts, buckets);
  lnq_kernel<<<M_DIM, 256, 0, stream>>>(x, gamma_f, Aq, scales);
  dim3 grid(N_DIM / 128, M_DIM / 128);
  gemm_i8_kernel<<<grid, 256, 0, stream>>>(Aq, Wq, scales, bias, counts, buckets, out);
}